// Round 10
// baseline (216.581 us; speedup 1.0000x reference)
//
#include <hip/hip_runtime.h>

#define N_NODES 100000
#define N_EDGES 1600000
#define D 64
#define N_BBOX 4096
#define CAP 64       // per-node slot capacity; deg ~ Poisson(16), P(>=64) ~ 1e-20
#define NBITW 3136   // words for N_NODES bits, padded
#define SLICE 12500  // N_NODES / 8 XCD slices
#define NSTRIPE 256  // edge stripes per slice
#define EPB (N_EDGES / NSTRIPE)  // 6250 edges per stripe
#define NTILE1 (N_NODES / 16)  // 6250
#define NTILE2 (N_BBOX / 16)   // 256

typedef short bf16x8 __attribute__((ext_vector_type(8)));
typedef float f32x4 __attribute__((ext_vector_type(4)));

__device__ __forceinline__ int bperm(int srclane, int v) {
  return __builtin_amdgcn_ds_bpermute(srclane << 2, v);
}
__device__ __forceinline__ float lrelu(float v) {
  return fmaxf(v, 0.01f * v);  // neg_slope 0.01 > 0
}
__device__ __forceinline__ bool testbit(const unsigned* bits, int i) {
  return (bits[i >> 5] >> (i & 31)) & 1u;
}
__device__ __forceinline__ short f2bf(float f) {  // RNE fp32 -> bf16
  unsigned u = __float_as_uint(f);
  u += 0x7FFFu + ((u >> 16) & 1u);
  return (short)(u >> 16);
}

// ---- kernel 1: fused xprep (x->bf16) + bbox mark + W frag pack ----
// (cnt zeroed by the contiguous memset; edge-mark moved into scatterM where
// it is XCD-sliced by src -> local atomics.)
// Weight fragment table (fragment-major bf16): for layer l, mat m (0=rel,1=root),
// kh, quad, col, i: wf[l*8192 + m*4096 + kh*2048 + quad*512 + col*8 + i]
//   = bf16(W[k*64 + col]), k = kh*32 + quad*8 + i.
__global__ __launch_bounds__(256) void prep_kernel(const float4* __restrict__ x4,
                                                   bf16x8* __restrict__ xb,
                                                   const int* __restrict__ bbox,
                                                   unsigned* __restrict__ is_bbox_bits,
                                                   unsigned* __restrict__ needed_bits,
                                                   const float* __restrict__ W1rel,
                                                   const float* __restrict__ W1root,
                                                   const float* __restrict__ W2rel,
                                                   const float* __restrict__ W2root,
                                                   short* __restrict__ wf) {
  const int i = blockIdx.x * 256 + threadIdx.x;
  if (i < N_NODES * 8) {  // one 8-elem chunk per thread
    const float4 a = x4[i * 2], b = x4[i * 2 + 1];
    bf16x8 r;
    r[0] = f2bf(a.x); r[1] = f2bf(a.y); r[2] = f2bf(a.z); r[3] = f2bf(a.w);
    r[4] = f2bf(b.x); r[5] = f2bf(b.y); r[6] = f2bf(b.z); r[7] = f2bf(b.w);
    xb[i] = r;
  } else {
    const int t = i - N_NODES * 8;
    if (t < N_BBOX) {
      const int n = bbox[t];
      const unsigned m = 1u << (n & 31);
      atomicOr(&is_bbox_bits[n >> 5], m);
      atomicOr(&needed_bits[n >> 5], m);
    } else if (t < N_BBOX + 4 * 4096) {
      const int t2 = t - N_BBOX;           // [0, 16384)
      const int layer = t2 >> 13;          // 0: W1, 1: W2
      const int r = t2 & 8191;
      const int m = r >> 12;               // 0: rel, 1: root
      const int e = r & 4095;
      const int kh = e >> 11, quad = (e >> 9) & 3;
      const int col = (e >> 3) & 63, ii = e & 7;
      const int k = kh * 32 + quad * 8 + ii;
      const float* W = layer ? (m ? W2root : W2rel) : (m ? W1root : W1rel);
      wf[t2] = f2bf(W[k * 64 + col]);
    }
  }
}

// ---- kernel 2: XCD-sliced scatter-all + sliced needed-mark ----
// blk&7 = slice (XCD round-robin heuristic; correctness mapping-independent).
// Each block scans one 6250-edge stripe; keeps dst-in-slice for slot scatter
// (cnt/slots atomics local to one XCD's L2: 50KB + 3.2MB slice) and
// src-in-slice for needed-mark (local atomicOr). Edge stream re-read 8x ->
// served by shared L3. No needed-filter: gd1 filters rows by needed_bits.
__global__ __launch_bounds__(256) void scatterM_kernel(
    const int* __restrict__ src, const int* __restrict__ dst,
    const unsigned* __restrict__ is_bbox_bits,
    unsigned* __restrict__ needed_bits, int* __restrict__ cnt,
    int* __restrict__ slots) {
  const int sl = blockIdx.x & 7;
  const int stripe = blockIdx.x >> 3;  // 0..NSTRIPE-1
  const int lo = sl * SLICE;
  const int hi = lo + SLICE;
  const int e0 = stripe * EPB;
  for (int i = threadIdx.x; i < EPB; i += 256) {
    const int e = e0 + i;
    const int d = dst[e];
    const int s = src[e];
    if (d >= lo && d < hi) {  // slot scatter, local atomics
      const int pos = atomicAdd(&cnt[d], 1);
      if (pos < CAP) slots[(size_t)d * CAP + pos] = s;
    }
    if (s >= lo && s < hi) {  // needed mark, local atomics (~4% of edges hit)
      if (testbit(is_bbox_bits, d))
        atomicOr(&needed_bits[s >> 5], 1u << (s & 31));
    }
  }
}

// ---- wave-cooperative gather-sum (round-3 verified): 4-deep batches,
// wave-uniform skip of dead sub-batches. On exit accf[i] of lane (g=0,c)
// holds element c*8+i of the row-sum, replicated across 8 groups.
__device__ __forceinline__ void gather_rows(const uint4* __restrict__ rows,
                                            const int* __restrict__ slots,
                                            int node, int n, int lane,
                                            float accf[8]) {
  const int g = lane >> 3, c = lane & 7;
  const int myslot = (lane < n) ? slots[(size_t)node * CAP + lane] : 0;
#pragma unroll
  for (int i = 0; i < 8; i++) accf[i] = 0.f;
  for (int e0 = 0; e0 < n; e0 += 32) {
    const int rem = n - e0;  // wave-uniform
    int idx[4], s[4];
    uint4 v[4];
#pragma unroll
    for (int u = 0; u < 4; u++)
      if (u * 8 < rem) {
        idx[u] = e0 + u * 8 + g;
        s[u] = bperm(idx[u], myslot);
      }
#pragma unroll
    for (int u = 0; u < 4; u++)
      if (u * 8 < rem) {
        v[u] = make_uint4(0u, 0u, 0u, 0u);
        if (idx[u] < n) v[u] = rows[(size_t)s[u] * 8 + c];
      }
#pragma unroll
    for (int u = 0; u < 4; u++)
      if (u * 8 < rem) {
        accf[0] += __uint_as_float(v[u].x << 16);
        accf[1] += __uint_as_float(v[u].x & 0xFFFF0000u);
        accf[2] += __uint_as_float(v[u].y << 16);
        accf[3] += __uint_as_float(v[u].y & 0xFFFF0000u);
        accf[4] += __uint_as_float(v[u].z << 16);
        accf[5] += __uint_as_float(v[u].z & 0xFFFF0000u);
        accf[6] += __uint_as_float(v[u].w << 16);
        accf[7] += __uint_as_float(v[u].w & 0xFFFF0000u);
      }
  }
#pragma unroll
  for (int off = 8; off < 64; off <<= 1)
#pragma unroll
    for (int i = 0; i < 8; i++) accf[i] += __shfl_xor(accf[i], off);
}

// ---- kernel 3: layer-1 gather -> LDS -> ONE barrier -> MFMA -> hb ----
// One tile per block. Rows are gathered only if needed (scatter-all means
// cnt>0 for almost every node; needed_bits is the work filter now).
__global__ __launch_bounds__(256) void gd1_kernel(
    const uint4* __restrict__ xb4, const short* __restrict__ xb,
    const unsigned* __restrict__ needed_bits, const int* __restrict__ cnt,
    const int* __restrict__ slots, const short* __restrict__ wf1,
    const float* __restrict__ b1, short* __restrict__ hb) {
  __shared__ __align__(16) short aggt[16][72];
  const int t = threadIdx.x;
  const int lane = t & 63;
  const int wid = t >> 6;  // 0..3 = wave id = nt quadrant
  const int cn = lane & 15, quad = lane >> 4;
  const int col = wid * 16 + cn;
  const int node0 = blockIdx.x * 16;  // grid == NTILE1 exactly

  const bf16x8* wfv = (const bf16x8*)wf1;
  bf16x8 brel[2], broot[2];
#pragma unroll
  for (int kh = 0; kh < 2; kh++) {
    brel[kh] = wfv[(kh * 4 + quad) * 64 + col];
    broot[kh] = wfv[((2 + kh) * 4 + quad) * 64 + col];
  }
  const float bj = b1[col];

#pragma unroll
  for (int r4 = 0; r4 < 4; r4++) {
    const int row = wid * 4 + r4;
    const int node = node0 + row;
    int n = 0;
    if (testbit(needed_bits, node)) {  // work filter (scatter-all fills cnt for everyone)
      n = cnt[node];
      n = (n > CAP) ? CAP : n;
    }
    if (n == 0) {  // non-needed or deg-0: zero row
      if (lane < 8) {
        bf16x8 z = {0, 0, 0, 0, 0, 0, 0, 0};
        *(bf16x8*)(&aggt[row][lane * 8]) = z;
      }
      continue;
    }
    float accf[8];
    gather_rows(xb4, slots, node, n, lane, accf);
    if (lane < 8) {
      bf16x8 r;
#pragma unroll
      for (int i = 0; i < 8; i++) r[i] = f2bf(accf[i]);
      *(bf16x8*)(&aggt[row][lane * 8]) = r;
    }
  }
  __syncthreads();  // the only barrier

  const int mrow = node0 + cn;
  const bool ndrow = testbit(needed_bits, mrow);
  f32x4 acc = {};
#pragma unroll
  for (int kh = 0; kh < 2; kh++) {
    const bf16x8 a_agg = *(const bf16x8*)(&aggt[cn][kh * 32 + quad * 8]);
    bf16x8 a_x = {0, 0, 0, 0, 0, 0, 0, 0};
    if (ndrow)
      a_x = *(const bf16x8*)(xb + (size_t)mrow * D + kh * 32 + quad * 8);
    acc = __builtin_amdgcn_mfma_f32_16x16x32_bf16(a_agg, brel[kh], acc, 0, 0, 0);
    acc = __builtin_amdgcn_mfma_f32_16x16x32_bf16(a_x, broot[kh], acc, 0, 0, 0);
  }
#pragma unroll
  for (int r = 0; r < 4; r++) {
    const int row = quad * 4 + r;
    if (testbit(needed_bits, node0 + row))
      hb[(size_t)(node0 + row) * D + col] = f2bf(lrelu(acc[r] + bj));
  }
}

// ---- kernel 4: layer-2 for bbox rows ----
__global__ __launch_bounds__(256) void gd2_kernel(
    const uint4* __restrict__ hb4, const short* __restrict__ hb,
    const int* __restrict__ cnt, const int* __restrict__ slots,
    const int* __restrict__ bbox, const short* __restrict__ wf2,
    const float* __restrict__ b2, float* __restrict__ out) {
  __shared__ __align__(16) short aggt[16][72];
  __shared__ int nodes_s[16];
  const int t = threadIdx.x;
  const int lane = t & 63;
  const int wid = t >> 6;
  const int cn = lane & 15, quad = lane >> 4;
  const int col = wid * 16 + cn;
  const int t0 = blockIdx.x * 16;  // grid = NTILE2 exactly

  if (t < 16) nodes_s[t] = bbox[t0 + t];

  const bf16x8* wfv = (const bf16x8*)wf2;
  bf16x8 brel[2], broot[2];
#pragma unroll
  for (int kh = 0; kh < 2; kh++) {
    brel[kh] = wfv[(kh * 4 + quad) * 64 + col];
    broot[kh] = wfv[((2 + kh) * 4 + quad) * 64 + col];
  }
  const float bj = b2[col];
  __syncthreads();

#pragma unroll
  for (int r4 = 0; r4 < 4; r4++) {
    const int row = wid * 4 + r4;
    const int node = nodes_s[row];
    int n = cnt[node];
    n = (n > CAP) ? CAP : n;
    if (n == 0) {
      if (lane < 8) {
        bf16x8 z = {0, 0, 0, 0, 0, 0, 0, 0};
        *(bf16x8*)(&aggt[row][lane * 8]) = z;
      }
      continue;
    }
    float accf[8];
    gather_rows(hb4, slots, node, n, lane, accf);
    if (lane < 8) {
      bf16x8 r;
#pragma unroll
      for (int i = 0; i < 8; i++) r[i] = f2bf(accf[i]);
      *(bf16x8*)(&aggt[row][lane * 8]) = r;
    }
  }
  __syncthreads();

  const int rnode = nodes_s[cn];  // root row for A[m=cn]
  f32x4 acc = {};
#pragma unroll
  for (int kh = 0; kh < 2; kh++) {
    const bf16x8 a_agg = *(const bf16x8*)(&aggt[cn][kh * 32 + quad * 8]);
    const bf16x8 a_h = *(const bf16x8*)(hb + (size_t)rnode * D + kh * 32 + quad * 8);
    acc = __builtin_amdgcn_mfma_f32_16x16x32_bf16(a_agg, brel[kh], acc, 0, 0, 0);
    acc = __builtin_amdgcn_mfma_f32_16x16x32_bf16(a_h, broot[kh], acc, 0, 0, 0);
  }
#pragma unroll
  for (int r = 0; r < 4; r++) {
    const int row = quad * 4 + r;
    out[(size_t)(t0 + row) * D + col] = lrelu(acc[r] + bj);
  }
}

// ---------------- launch ----------------

extern "C" void kernel_launch(void* const* d_in, const int* in_sizes, int n_in,
                              void* d_out, int out_size, void* d_ws, size_t ws_size,
                              hipStream_t stream) {
  const float* x = (const float*)d_in[0];
  const int* ei = (const int*)d_in[1];
  const int* src = ei;
  const int* dst = ei + N_EDGES;
  const int* bbox = (const int*)d_in[2];
  const float* W1rel = (const float*)d_in[3];
  const float* b1 = (const float*)d_in[4];
  const float* W1root = (const float*)d_in[5];
  const float* W2rel = (const float*)d_in[6];
  const float* b2 = (const float*)d_in[7];
  const float* W2root = (const float*)d_in[8];
  float* out = (float*)d_out;

  char* ws = (char*)d_ws;
  size_t off = 0;
  auto alloc = [&](size_t bytes) -> char* {
    char* p = ws + off;
    off = (off + bytes + 511) & ~(size_t)511;
    return p;
  };
  // contiguous zero region: bitmasks + cnt (~425 KB, one memset)
  unsigned* is_bbox_bits = (unsigned*)alloc(NBITW * sizeof(unsigned));
  unsigned* needed_bits = (unsigned*)alloc(NBITW * sizeof(unsigned));
  int* cnt = (int*)alloc(N_NODES * sizeof(int));
  char* zero_end = ws + off;
  int* slots = (int*)alloc((size_t)N_NODES * CAP * sizeof(int));          // 25.6 MB
  short* xb = (short*)alloc((size_t)N_NODES * D * sizeof(short));         // 12.8 MB
  short* hb = (short*)alloc((size_t)N_NODES * D * sizeof(short));         // 12.8 MB
  short* wf = (short*)alloc((size_t)4 * 4096 * sizeof(short));            // 32 KB

  hipMemsetAsync(is_bbox_bits, 0, (size_t)(zero_end - (char*)is_bbox_bits), stream);
  prep_kernel<<<(N_NODES * 8 + N_BBOX + 4 * 4096 + 255) / 256, 256, 0, stream>>>(
      (const float4*)x, (bf16x8*)xb, bbox, is_bbox_bits, needed_bits,
      W1rel, W1root, W2rel, W2root, wf);
  scatterM_kernel<<<8 * NSTRIPE, 256, 0, stream>>>(src, dst, is_bbox_bits,
                                                   needed_bits, cnt, slots);
  gd1_kernel<<<NTILE1, 256, 0, stream>>>((const uint4*)xb, xb, needed_bits, cnt,
                                         slots, wf, b1, hb);
  gd2_kernel<<<NTILE2, 256, 0, stream>>>((const uint4*)hb, hb, cnt, slots, bbox,
                                         wf + 8192, b2, out);
}

// Round 11
// 190.938 us; speedup vs baseline: 1.1343x; 1.1343x over previous
//
#include <hip/hip_runtime.h>

#define N_NODES 100000
#define N_EDGES 1600000
#define D 64
#define N_BBOX 4096
#define CAP 64       // per-node slot capacity; deg ~ Poisson(16), P(>=64) ~ 1e-20
#define NBITW 3136   // words for N_NODES bits, padded
#define NTILE1 (N_NODES / 16)  // 6250
#define NTILE2 (N_BBOX / 16)   // 256

typedef short bf16x8 __attribute__((ext_vector_type(8)));
typedef float f32x4 __attribute__((ext_vector_type(4)));
typedef float f32x2 __attribute__((ext_vector_type(2)));

__device__ __forceinline__ int bperm(int srclane, int v) {
  return __builtin_amdgcn_ds_bpermute(srclane << 2, v);
}
__device__ __forceinline__ float lrelu(float v) {
  return fmaxf(v, 0.01f * v);  // neg_slope 0.01 > 0
}
__device__ __forceinline__ bool testbit(const unsigned* bits, int i) {
  return (bits[i >> 5] >> (i & 31)) & 1u;
}
__device__ __forceinline__ short f2bf(float f) {  // RNE fp32 -> bf16
  unsigned u = __float_as_uint(f);
  u += 0x7FFFu + ((u >> 16) & 1u);
  return (short)(u >> 16);
}

// ---- kernel 1: bbox marking (after memset of the two bitmasks) ----
__global__ __launch_bounds__(256) void mark_bbox_kernel(
    const int* __restrict__ bbox, unsigned* __restrict__ is_bbox_bits,
    unsigned* __restrict__ needed_bits) {
  const int t = blockIdx.x * 256 + threadIdx.x;  // grid covers N_BBOX exactly
  const int n = bbox[t];
  const unsigned m = 1u << (n & 31);
  atomicOr(&is_bbox_bits[n >> 5], m);
  atomicOr(&needed_bits[n >> 5], m);
}

// ---- kernel 2: fused xprep (x->bf16 AND x->fp8) + cnt zero + W pack + edge mark ----
// xb8: e4m3 copy of x (64B/row = ONE cache line) for the layer-1 neighbor-sum
// gather; root term / weights / hb stay bf16. HW RNE cvt (gfx950 OCP e4m3).
__global__ __launch_bounds__(256) void prep_kernel(const float4* __restrict__ x4,
                                                   bf16x8* __restrict__ xb,
                                                   uint2* __restrict__ xb8v,
                                                   const int* __restrict__ src,
                                                   const int* __restrict__ dst,
                                                   const unsigned* __restrict__ is_bbox_bits,
                                                   unsigned* __restrict__ needed_bits,
                                                   int* __restrict__ cnt,
                                                   const float* __restrict__ W1rel,
                                                   const float* __restrict__ W1root,
                                                   const float* __restrict__ W2rel,
                                                   const float* __restrict__ W2root,
                                                   short* __restrict__ wf) {
  const int i = blockIdx.x * 256 + threadIdx.x;
  if (i < N_NODES) cnt[i] = 0;
  if (i < N_NODES * 8) {  // one 8-elem chunk per thread
    const float4 a = x4[i * 2], b = x4[i * 2 + 1];
    bf16x8 r;
    r[0] = f2bf(a.x); r[1] = f2bf(a.y); r[2] = f2bf(a.z); r[3] = f2bf(a.w);
    r[4] = f2bf(b.x); r[5] = f2bf(b.y); r[6] = f2bf(b.z); r[7] = f2bf(b.w);
    xb[i] = r;
    int lo = __builtin_amdgcn_cvt_pk_fp8_f32(a.x, a.y, 0, false);
    lo = __builtin_amdgcn_cvt_pk_fp8_f32(a.z, a.w, lo, true);
    int hi = __builtin_amdgcn_cvt_pk_fp8_f32(b.x, b.y, 0, false);
    hi = __builtin_amdgcn_cvt_pk_fp8_f32(b.z, b.w, hi, true);
    uint2 w;
    w.x = (unsigned)lo;
    w.y = (unsigned)hi;
    xb8v[i] = w;
  } else {
    const int t = i - N_NODES * 8;
    if (t < 4 * 4096) {  // weight fragment pack
      const int layer = t >> 13;           // 0: W1, 1: W2
      const int r = t & 8191;
      const int m = r >> 12;               // 0: rel, 1: root
      const int e = r & 4095;
      const int kh = e >> 11, quad = (e >> 9) & 3;
      const int col = (e >> 3) & 63, ii = e & 7;
      const int k = kh * 32 + quad * 8 + ii;
      const float* W = layer ? (m ? W2root : W2rel) : (m ? W1root : W1rel);
      wf[t] = f2bf(W[k * 64 + col]);
    } else {
      const int e = t - 4 * 4096;          // edge mark, [0, N_EDGES)
      if (e < N_EDGES) {
        if (testbit(is_bbox_bits, dst[e]))  // ~4%; bitmask L1/L2-hot
          atomicOr(&needed_bits[src[e] >> 5], 1u << (src[e] & 31));
      }
    }
  }
}

// ---- kernel 3: direct slot scatter (round-9 verified, 53us) ----
__global__ __launch_bounds__(256) void scatter_kernel(
    const int* __restrict__ src, const int* __restrict__ dst,
    const unsigned* __restrict__ needed_bits, int* __restrict__ cnt,
    int* __restrict__ slots) {
  const int e = blockIdx.x * 256 + threadIdx.x;  // grid covers N_EDGES exactly
  const int d = dst[e];
  if (!testbit(needed_bits, d)) return;  // ~50% discard
  const int s = src[e];
  const int pos = atomicAdd(&cnt[d], 1);
  if (pos < CAP) slots[(size_t)d * CAP + pos] = s;
}

// ---- fp8 wave-cooperative gather-sum: rows are 64B (uint2/lane), HW unpack.
// Same schedule as the verified bf16 gather_rows (4-deep batches, uniform
// skip). On exit accf[i] of lane (g=0,c) holds element c*8+i, replicated.
__device__ __forceinline__ void gather_rows8(const uint2* __restrict__ rows,
                                             const int* __restrict__ slots,
                                             int node, int n, int lane,
                                             float accf[8]) {
  const int g = lane >> 3, c = lane & 7;
  const int myslot = (lane < n) ? slots[(size_t)node * CAP + lane] : 0;
#pragma unroll
  for (int i = 0; i < 8; i++) accf[i] = 0.f;
  for (int e0 = 0; e0 < n; e0 += 32) {
    const int rem = n - e0;  // wave-uniform
    int idx[4], s[4];
    uint2 v[4];
#pragma unroll
    for (int u = 0; u < 4; u++)
      if (u * 8 < rem) {
        idx[u] = e0 + u * 8 + g;
        s[u] = bperm(idx[u], myslot);
      }
#pragma unroll
    for (int u = 0; u < 4; u++)
      if (u * 8 < rem) {
        v[u] = make_uint2(0u, 0u);  // fp8 0x00 == +0.0
        if (idx[u] < n) v[u] = rows[(size_t)s[u] * 8 + c];
      }
#pragma unroll
    for (int u = 0; u < 4; u++)
      if (u * 8 < rem) {
        f32x2 p;
        p = __builtin_amdgcn_cvt_pk_f32_fp8(v[u].x, false);
        accf[0] += p.x; accf[1] += p.y;
        p = __builtin_amdgcn_cvt_pk_f32_fp8(v[u].x, true);
        accf[2] += p.x; accf[3] += p.y;
        p = __builtin_amdgcn_cvt_pk_f32_fp8(v[u].y, false);
        accf[4] += p.x; accf[5] += p.y;
        p = __builtin_amdgcn_cvt_pk_f32_fp8(v[u].y, true);
        accf[6] += p.x; accf[7] += p.y;
      }
  }
#pragma unroll
  for (int off = 8; off < 64; off <<= 1)
#pragma unroll
    for (int i = 0; i < 8; i++) accf[i] += __shfl_xor(accf[i], off);
}

// ---- bf16 gather (unchanged; used by layer 2 on hb) ----
__device__ __forceinline__ void gather_rows(const uint4* __restrict__ rows,
                                            const int* __restrict__ slots,
                                            int node, int n, int lane,
                                            float accf[8]) {
  const int g = lane >> 3, c = lane & 7;
  const int myslot = (lane < n) ? slots[(size_t)node * CAP + lane] : 0;
#pragma unroll
  for (int i = 0; i < 8; i++) accf[i] = 0.f;
  for (int e0 = 0; e0 < n; e0 += 32) {
    const int rem = n - e0;  // wave-uniform
    int idx[4], s[4];
    uint4 v[4];
#pragma unroll
    for (int u = 0; u < 4; u++)
      if (u * 8 < rem) {
        idx[u] = e0 + u * 8 + g;
        s[u] = bperm(idx[u], myslot);
      }
#pragma unroll
    for (int u = 0; u < 4; u++)
      if (u * 8 < rem) {
        v[u] = make_uint4(0u, 0u, 0u, 0u);
        if (idx[u] < n) v[u] = rows[(size_t)s[u] * 8 + c];
      }
#pragma unroll
    for (int u = 0; u < 4; u++)
      if (u * 8 < rem) {
        accf[0] += __uint_as_float(v[u].x << 16);
        accf[1] += __uint_as_float(v[u].x & 0xFFFF0000u);
        accf[2] += __uint_as_float(v[u].y << 16);
        accf[3] += __uint_as_float(v[u].y & 0xFFFF0000u);
        accf[4] += __uint_as_float(v[u].z << 16);
        accf[5] += __uint_as_float(v[u].z & 0xFFFF0000u);
        accf[6] += __uint_as_float(v[u].w << 16);
        accf[7] += __uint_as_float(v[u].w & 0xFFFF0000u);
      }
  }
#pragma unroll
  for (int off = 8; off < 64; off <<= 1)
#pragma unroll
    for (int i = 0; i < 8; i++) accf[i] += __shfl_xor(accf[i], off);
}

// ---- kernel 4: layer-1 fp8 gather -> LDS -> ONE barrier -> MFMA -> hb ----
__global__ __launch_bounds__(256) void gd1_kernel(
    const uint2* __restrict__ xb8v, const short* __restrict__ xb,
    const unsigned* __restrict__ needed_bits, const int* __restrict__ cnt,
    const int* __restrict__ slots, const short* __restrict__ wf1,
    const float* __restrict__ b1, short* __restrict__ hb) {
  __shared__ __align__(16) short aggt[16][72];
  const int t = threadIdx.x;
  const int lane = t & 63;
  const int wid = t >> 6;  // 0..3 = wave id = nt quadrant
  const int cn = lane & 15, quad = lane >> 4;
  const int col = wid * 16 + cn;
  const int node0 = blockIdx.x * 16;  // grid == NTILE1 exactly

  const bf16x8* wfv = (const bf16x8*)wf1;
  bf16x8 brel[2], broot[2];
#pragma unroll
  for (int kh = 0; kh < 2; kh++) {
    brel[kh] = wfv[(kh * 4 + quad) * 64 + col];
    broot[kh] = wfv[((2 + kh) * 4 + quad) * 64 + col];
  }
  const float bj = b1[col];

#pragma unroll
  for (int r4 = 0; r4 < 4; r4++) {
    const int row = wid * 4 + r4;
    const int node = node0 + row;
    int n = cnt[node];
    n = (n > CAP) ? CAP : n;
    if (n == 0) {  // non-needed (filtered) or deg-0: zero row
      if (lane < 8) {
        bf16x8 z = {0, 0, 0, 0, 0, 0, 0, 0};
        *(bf16x8*)(&aggt[row][lane * 8]) = z;
      }
      continue;
    }
    float accf[8];
    gather_rows8(xb8v, slots, node, n, lane, accf);
    if (lane < 8) {
      bf16x8 r;
#pragma unroll
      for (int i = 0; i < 8; i++) r[i] = f2bf(accf[i]);
      *(bf16x8*)(&aggt[row][lane * 8]) = r;
    }
  }
  __syncthreads();  // the only barrier

  const int mrow = node0 + cn;
  const bool ndrow = testbit(needed_bits, mrow);
  f32x4 acc = {};
#pragma unroll
  for (int kh = 0; kh < 2; kh++) {
    const bf16x8 a_agg = *(const bf16x8*)(&aggt[cn][kh * 32 + quad * 8]);
    bf16x8 a_x = {0, 0, 0, 0, 0, 0, 0, 0};
    if (ndrow)
      a_x = *(const bf16x8*)(xb + (size_t)mrow * D + kh * 32 + quad * 8);
    acc = __builtin_amdgcn_mfma_f32_16x16x32_bf16(a_agg, brel[kh], acc, 0, 0, 0);
    acc = __builtin_amdgcn_mfma_f32_16x16x32_bf16(a_x, broot[kh], acc, 0, 0, 0);
  }
#pragma unroll
  for (int r = 0; r < 4; r++) {
    const int row = quad * 4 + r;
    if (testbit(needed_bits, node0 + row))
      hb[(size_t)(node0 + row) * D + col] = f2bf(lrelu(acc[r] + bj));
  }
}

// ---- kernel 5: layer-2 for bbox rows (bf16 gather on hb) ----
__global__ __launch_bounds__(256) void gd2_kernel(
    const uint4* __restrict__ hb4, const short* __restrict__ hb,
    const int* __restrict__ cnt, const int* __restrict__ slots,
    const int* __restrict__ bbox, const short* __restrict__ wf2,
    const float* __restrict__ b2, float* __restrict__ out) {
  __shared__ __align__(16) short aggt[16][72];
  __shared__ int nodes_s[16];
  const int t = threadIdx.x;
  const int lane = t & 63;
  const int wid = t >> 6;
  const int cn = lane & 15, quad = lane >> 4;
  const int col = wid * 16 + cn;
  const int t0 = blockIdx.x * 16;  // grid = NTILE2 exactly

  if (t < 16) nodes_s[t] = bbox[t0 + t];

  const bf16x8* wfv = (const bf16x8*)wf2;
  bf16x8 brel[2], broot[2];
#pragma unroll
  for (int kh = 0; kh < 2; kh++) {
    brel[kh] = wfv[(kh * 4 + quad) * 64 + col];
    broot[kh] = wfv[((2 + kh) * 4 + quad) * 64 + col];
  }
  const float bj = b2[col];
  __syncthreads();

#pragma unroll
  for (int r4 = 0; r4 < 4; r4++) {
    const int row = wid * 4 + r4;
    const int node = nodes_s[row];
    int n = cnt[node];
    n = (n > CAP) ? CAP : n;
    if (n == 0) {
      if (lane < 8) {
        bf16x8 z = {0, 0, 0, 0, 0, 0, 0, 0};
        *(bf16x8*)(&aggt[row][lane * 8]) = z;
      }
      continue;
    }
    float accf[8];
    gather_rows(hb4, slots, node, n, lane, accf);
    if (lane < 8) {
      bf16x8 r;
#pragma unroll
      for (int i = 0; i < 8; i++) r[i] = f2bf(accf[i]);
      *(bf16x8*)(&aggt[row][lane * 8]) = r;
    }
  }
  __syncthreads();

  const int rnode = nodes_s[cn];  // root row for A[m=cn]
  f32x4 acc = {};
#pragma unroll
  for (int kh = 0; kh < 2; kh++) {
    const bf16x8 a_agg = *(const bf16x8*)(&aggt[cn][kh * 32 + quad * 8]);
    const bf16x8 a_h = *(const bf16x8*)(hb + (size_t)rnode * D + kh * 32 + quad * 8);
    acc = __builtin_amdgcn_mfma_f32_16x16x32_bf16(a_agg, brel[kh], acc, 0, 0, 0);
    acc = __builtin_amdgcn_mfma_f32_16x16x32_bf16(a_h, broot[kh], acc, 0, 0, 0);
  }
#pragma unroll
  for (int r = 0; r < 4; r++) {
    const int row = quad * 4 + r;
    out[(size_t)(t0 + row) * D + col] = lrelu(acc[r] + bj);
  }
}

// ---------------- launch ----------------

extern "C" void kernel_launch(void* const* d_in, const int* in_sizes, int n_in,
                              void* d_out, int out_size, void* d_ws, size_t ws_size,
                              hipStream_t stream) {
  const float* x = (const float*)d_in[0];
  const int* ei = (const int*)d_in[1];
  const int* src = ei;
  const int* dst = ei + N_EDGES;
  const int* bbox = (const int*)d_in[2];
  const float* W1rel = (const float*)d_in[3];
  const float* b1 = (const float*)d_in[4];
  const float* W1root = (const float*)d_in[5];
  const float* W2rel = (const float*)d_in[6];
  const float* b2 = (const float*)d_in[7];
  const float* W2root = (const float*)d_in[8];
  float* out = (float*)d_out;

  char* ws = (char*)d_ws;
  size_t off = 0;
  auto alloc = [&](size_t bytes) -> char* {
    char* p = ws + off;
    off = (off + bytes + 511) & ~(size_t)511;
    return p;
  };
  // contiguous zero region: just the two bitmasks (25 KB); cnt zeroed in prep
  unsigned* is_bbox_bits = (unsigned*)alloc(NBITW * sizeof(unsigned));
  unsigned* needed_bits = (unsigned*)alloc(NBITW * sizeof(unsigned));
  char* zero_end = ws + off;
  int* cnt = (int*)alloc(N_NODES * sizeof(int));
  int* slots = (int*)alloc((size_t)N_NODES * CAP * sizeof(int));          // 25.6 MB
  short* xb = (short*)alloc((size_t)N_NODES * D * sizeof(short));         // 12.8 MB
  unsigned char* xb8 = (unsigned char*)alloc((size_t)N_NODES * D);        // 6.4 MB
  short* hb = (short*)alloc((size_t)N_NODES * D * sizeof(short));         // 12.8 MB
  short* wf = (short*)alloc((size_t)4 * 4096 * sizeof(short));            // 32 KB

  hipMemsetAsync(is_bbox_bits, 0, (size_t)(zero_end - (char*)is_bbox_bits), stream);
  mark_bbox_kernel<<<N_BBOX / 256, 256, 0, stream>>>(bbox, is_bbox_bits,
                                                     needed_bits);
  prep_kernel<<<(N_NODES * 8 + 4 * 4096 + N_EDGES + 255) / 256, 256, 0, stream>>>(
      (const float4*)x, (bf16x8*)xb, (uint2*)xb8, src, dst, is_bbox_bits,
      needed_bits, cnt, W1rel, W1root, W2rel, W2root, wf);
  scatter_kernel<<<N_EDGES / 256, 256, 0, stream>>>(src, dst, needed_bits, cnt,
                                                    slots);
  gd1_kernel<<<NTILE1, 256, 0, stream>>>((const uint2*)xb8, xb, needed_bits, cnt,
                                         slots, wf, b1, hb);
  gd2_kernel<<<NTILE2, 256, 0, stream>>>((const uint4*)hb, hb, cnt, slots, bbox,
                                         wf + 8192, b2, out);
}